// Round 2
// baseline (541.451 us; speedup 1.0000x reference)
//
#include <hip/hip_runtime.h>
#include <hip/hip_bf16.h>

// GraphSageLayer on MI355X. B=4, N=4096, D_IN=REP=D_OUT=128.
// proj (nodes->3 reps, bf16) -> agg (adj @ in_rep, adj^T @ out_rep) -> final (concat @ W_upd^T, tanh).
// All matmuls via v_mfma_f32_16x16x32_bf16; fp32 converted to bf16 in flight.
//
// R4 (DRAM-granule fix): R3 proved occupancy is NOT the limit (2x waves -> +0%:
// HBM pinned at ~2.2 TB/s = 35% of achievable with all pipes idle). Theory: all
// adj accesses are 16KB-strided with 256-512B contiguous granules -> DRAM
// page/channel efficiency caps supply. Fix = widen granules to ~1KB:
//  - agg_in : i-panel 64, BK 256 (1KB/row). Single-buffer LDS [64][264] (33.8KB)
//             + register double-buffer (pf/a_nxt prefetch). splitk2, grid 512.
//  - agg_out: i-panel 256 (1KB/row transposed stage), 512-thr blocks, LDS
//             [256][68] (34.8KB) single-buffer, conflict-free pair writes.
//             splitk4, grid 256 (1 block/CU, 8 waves).
//  - both: bijective XCD-chunked swizzle clustering same (b, k-chunk) per XCD.
//  - final6 sums 2 in-partials + 4 out-partials (fp32, deterministic).
//  - ws need 60MB; guarded fallback to proven R3 44MB split path.

typedef __attribute__((ext_vector_type(8))) short short8;
typedef __attribute__((ext_vector_type(4))) float f32x4;
typedef __attribute__((ext_vector_type(4))) unsigned short u16x4;

#define MFMA(a, b, c) __builtin_amdgcn_mfma_f32_16x16x32_bf16(a, b, c, 0, 0, 0)

__device__ __forceinline__ unsigned short f2bf(float x) {
  union { float f; unsigned u; } v; v.f = x;
  unsigned r = v.u + 0x7FFFu + ((v.u >> 16) & 1u);   // RNE to bf16
  return (unsigned short)(r >> 16);
}

__device__ __forceinline__ short8 pack8(float4 a, float4 b) {
  short8 v;
  v[0] = (short)f2bf(a.x); v[1] = (short)f2bf(a.y); v[2] = (short)f2bf(a.z); v[3] = (short)f2bf(a.w);
  v[4] = (short)f2bf(b.x); v[5] = (short)f2bf(b.y); v[6] = (short)f2bf(b.z); v[7] = (short)f2bf(b.w);
  return v;
}

// ---------------------------------------------------------------------------
// Kernel 1: projections. rep = elu(nodes @ W^T + b). grid=(256 m-tiles, 3).
// ---------------------------------------------------------------------------
__global__ __launch_bounds__(256) void proj_kernel(
    const float* __restrict__ nodes,   // [16384][128]
    const float* __restrict__ W_in, const float* __restrict__ b_in,
    const float* __restrict__ W_out, const float* __restrict__ b_out,
    const float* __restrict__ W_node, const float* __restrict__ b_node,
    unsigned short* __restrict__ in_rep_t,   // [4][128][4096]
    unsigned short* __restrict__ out_rep_t,  // [4][128][4096]
    unsigned short* __restrict__ node_rep)   // [4][4096][128]
{
  const int wsel = blockIdx.y;
  const float* W    = (wsel == 0) ? W_in  : (wsel == 1) ? W_out  : W_node;
  const float* bias = (wsel == 0) ? b_in  : (wsel == 1) ? b_out  : b_node;

  const int tid  = threadIdx.x;
  const int lane = tid & 63;
  const int w    = tid >> 6;
  const int q    = lane >> 4;
  const int r15  = lane & 15;
  const int m0   = blockIdx.x * 64 + w * 16;

  f32x4 acc[8];
#pragma unroll
  for (int nt = 0; nt < 8; ++nt) acc[nt] = (f32x4)0.0f;

  short8 a[4];
#pragma unroll
  for (int ks = 0; ks < 4; ++ks) {
    const float* p = nodes + (size_t)(m0 + r15) * 128 + ks * 32 + q * 8;
    a[ks] = pack8(*(const float4*)p, *(const float4*)(p + 4));
  }

#pragma unroll
  for (int ks = 0; ks < 4; ++ks)
#pragma unroll
    for (int nt = 0; nt < 8; ++nt) {
      const float* p = W + (size_t)(nt * 16 + r15) * 128 + ks * 32 + q * 8;
      short8 bv = pack8(*(const float4*)p, *(const float4*)(p + 4));
      acc[nt] = MFMA(a[ks], bv, acc[nt]);
    }

#pragma unroll
  for (int nt = 0; nt < 8; ++nt) {
    const int rcol = nt * 16 + r15;
    const float bv = bias[rcol];
    const int g0 = m0 + q * 4;
    float x[4];
#pragma unroll
    for (int c = 0; c < 4; ++c) {
      float t = acc[nt][c] + bv;
      x[c] = (t > 0.f) ? t : (expf(t) - 1.f);   // ELU
    }
    if (wsel < 2) {
      unsigned short* rep = (wsel == 0) ? in_rep_t : out_rep_t;
      const int b = g0 >> 12, j = g0 & 4095;
      u16x4 o;
#pragma unroll
      for (int c = 0; c < 4; ++c) o[c] = f2bf(x[c]);
      *(u16x4*)&rep[((size_t)b << 19) + (size_t)rcol * 4096 + j] = o;
    } else {
#pragma unroll
      for (int c = 0; c < 4; ++c)
        node_rep[(size_t)(g0 + c) * 128 + rcol] = f2bf(x[c]);
    }
  }
}

// ---------------------------------------------------------------------------
// Kernel 2a: in_agg[i,v] = sum_j adj[b][i][j] * in_rep[j][v].
// i-panel 64, BK=256 (1KB/row DRAM granule). LDS [64][264] bf16 single buffer
// (rot-4 conflict family), register dbuf: prefetch adj(e+1)->pf, rep(e+1)->a_nxt
// during MFMA(e); write after the read barrier. splitk2 -> fp32 partials.
// MFMA: A=rep_t rows (m=v), B=LDS tile (n=i).
// ---------------------------------------------------------------------------
#define INB_BK 256
#define INB_ST 264   // shorts per LDS row (132 dwords == 4 mod 32)

__global__ __launch_bounds__(256, 2) void agg_in_kernel(
    const float* __restrict__ adj,
    const unsigned short* __restrict__ in_rep_t,
    float* __restrict__ in0, float* __restrict__ in1)
{
  __shared__ unsigned short lds[64 * INB_ST];   // 33792 B

  const int bid = blockIdx.x;                 // 512 blocks
  const int sw  = (bid & 7) * 64 + (bid >> 3);  // XCD-chunk: 64 consecutive = one (kh,b)
  const int kh  = sw >> 8;
  const int t   = sw & 255;
  const int b   = t >> 6;
  const int n0  = (t & 63) * 64;
  const float* adjb = adj + ((size_t)b << 24);
  const unsigned short* rep = in_rep_t + ((size_t)b << 19);
  float* agg = (kh ? in1 : in0) + ((size_t)b << 19);

  const int tid  = threadIdx.x;
  const int lane = tid & 63;
  const int w    = tid >> 6;
  const int q    = lane >> 4;
  const int r15  = lane & 15;

  const unsigned short* arow[2];
#pragma unroll
  for (int mt = 0; mt < 2; ++mt)
    arow[mt] = rep + (size_t)(w * 32 + mt * 16 + r15) * 4096 + kh * 2048 + q * 8;

  // staging: thread = row sti, 64 consecutive cols (256 B); row granule = 1 KB
  const int sti = tid >> 2;
  const int ko  = (tid & 3) * 64;
  const float* ld = adjb + (size_t)(n0 + sti) * 4096 + kh * 2048 + ko;

  f32x4 acc[2][4];
#pragma unroll
  for (int mt = 0; mt < 2; ++mt)
#pragma unroll
    for (int nt = 0; nt < 4; ++nt) acc[mt][nt] = (f32x4)0.0f;

  float4 pf[16];
  short8 a_cur[16], a_nxt[16];

  auto stage_load = [&](int e) {
    const float* p = ld + e * INB_BK;
#pragma unroll
    for (int s = 0; s < 16; ++s) pf[s] = ((const float4*)p)[s];
  };
  auto stage_write = [&]() {
#pragma unroll
    for (int s = 0; s < 8; ++s)
      *(short8*)&lds[sti * INB_ST + ko + s * 8] = pack8(pf[2 * s], pf[2 * s + 1]);
  };
  auto load_a = [&](int e, short8* d) {
#pragma unroll
    for (int sub = 0; sub < 8; ++sub)
#pragma unroll
      for (int mt = 0; mt < 2; ++mt)
        d[sub * 2 + mt] = *(const short8*)(arow[mt] + e * INB_BK + sub * 32);
  };

  stage_load(0);
  load_a(0, a_cur);
  stage_write();
  __syncthreads();

  for (int e = 0; e < 8; ++e) {
    if (e < 7) { stage_load(e + 1); load_a(e + 1, a_nxt); }

#pragma unroll
    for (int sub = 0; sub < 8; ++sub)
#pragma unroll
      for (int nt = 0; nt < 4; ++nt) {
        short8 bv = *(const short8*)&lds[(nt * 16 + r15) * INB_ST + sub * 32 + q * 8];
        acc[0][nt] = MFMA(a_cur[sub * 2 + 0], bv, acc[0][nt]);
        acc[1][nt] = MFMA(a_cur[sub * 2 + 1], bv, acc[1][nt]);
      }
    __syncthreads();               // all reads of lds done
    if (e < 7) {
      stage_write();               // pf(e+1) -> lds
#pragma unroll
      for (int i = 0; i < 16; ++i) a_cur[i] = a_nxt[i];
      __syncthreads();             // writes visible before next reads
    }
  }

  // D: row(m=v)=q*4+reg, col(n=i)=r15 -> fp32 partial [i][v]
#pragma unroll
  for (int mt = 0; mt < 2; ++mt) {
    const int v0 = w * 32 + mt * 16 + q * 4;
#pragma unroll
    for (int nt = 0; nt < 4; ++nt) {
      const int i = n0 + nt * 16 + r15;
      *(f32x4*)&agg[(size_t)i * 128 + v0] = acc[mt][nt];
    }
  }
}

// ---------------------------------------------------------------------------
// Kernel 2b: out_agg[i,v] = sum_j adj[b][j][i] * out_rep[j][v].
// 512 threads, i-panel 256 (1KB/row stage granule), BJ=64 j/epoch, 16 epochs
// over a j-quarter (splitk4). LDS [256][68] bf16 single buffer; stage: thread
// owns j-pair p=tid&31 x 16 i (ch=tid>>5): pair-write bank=(2c+p)%32 ->
// conflict-free. Wave w: v-tiles {2vg,2vg+1} (vg=w>>1), i-tiles ng*8..+8
// (ng=w&1). MFMA: A=rep_t rows (m=v), B=LDS (n=i, k=j).
// ---------------------------------------------------------------------------
#define OUT_ST 68    // shorts per LDS row (34 dwords == 2 mod 32)

__global__ __launch_bounds__(512, 2) void agg_out_kernel(
    const float* __restrict__ adj,
    const unsigned short* __restrict__ out_rep_t,
    float* __restrict__ o0, float* __restrict__ o1,
    float* __restrict__ o2, float* __restrict__ o3)
{
  __shared__ unsigned short lds[256 * OUT_ST];   // 34816 B

  const int bid = blockIdx.x;                  // 256 blocks
  const int sw  = (bid & 7) * 32 + (bid >> 3); // XCD-chunk: 32 consecutive = 2 (b,kq) groups
  const int b   = sw >> 6;
  const int kq  = (sw >> 4) & 3;
  const int ip  = sw & 15;
  const int i0  = ip * 256;
  const int jb0 = kq * 1024;
  const float* adjb = adj + ((size_t)b << 24);
  const unsigned short* rep = out_rep_t + ((size_t)b << 19);
  float* agg = (kq == 0 ? o0 : kq == 1 ? o1 : kq == 2 ? o2 : o3) + ((size_t)b << 19);

  const int tid  = threadIdx.x;
  const int lane = tid & 63;
  const int w    = tid >> 6;       // 0..7
  const int q    = lane >> 4;
  const int r15  = lane & 15;
  const int vg   = w >> 1;         // v-group 0..3
  const int ng   = w & 1;          // i-half 0..1

  const unsigned short* arow[2];
#pragma unroll
  for (int mt = 0; mt < 2; ++mt)
    arow[mt] = rep + (size_t)(vg * 32 + mt * 16 + r15) * 4096 + jb0 + q * 8;

  // staging: thread = j rows {jb+2p, jb+2p+1} x 16 i (64 B each)
  const int p  = tid & 31;
  const int ch = tid >> 5;         // 0..15
  const float* ld0 = adjb + (size_t)(jb0 + 2 * p) * 4096 + i0 + ch * 16;
  const float* ld1 = ld0 + 4096;

  f32x4 acc[2][8];
#pragma unroll
  for (int mt = 0; mt < 2; ++mt)
#pragma unroll
    for (int nt = 0; nt < 8; ++nt) acc[mt][nt] = (f32x4)0.0f;

  float4 pf[8];

  auto stage_load = [&](int e) {
    const float* p0 = ld0 + (size_t)e * 64 * 4096;
    const float* p1 = ld1 + (size_t)e * 64 * 4096;
#pragma unroll
    for (int s = 0; s < 4; ++s) { pf[s] = ((const float4*)p0)[s]; pf[4 + s] = ((const float4*)p1)[s]; }
  };
  auto stage_write = [&]() {
    const float* r0 = (const float*)&pf[0];   // row j=2p, 16 i
    const float* r1 = (const float*)&pf[4];   // row j=2p+1
#pragma unroll
    for (int c = 0; c < 16; ++c) {
      unsigned v = (unsigned)f2bf(r0[c]) | ((unsigned)f2bf(r1[c]) << 16);
      *(unsigned*)&lds[(ch * 16 + c) * OUT_ST + 2 * p] = v;   // LDS[i_local][j_local]
    }
  };

  stage_load(0);
  stage_write();
  __syncthreads();

  for (int e = 0; e < 16; ++e) {
    if (e < 15) stage_load(e + 1);

    short8 a00 = *(const short8*)(arow[0] + e * 64);
    short8 a01 = *(const short8*)(arow[0] + e * 64 + 32);
    short8 a10 = *(const short8*)(arow[1] + e * 64);
    short8 a11 = *(const short8*)(arow[1] + e * 64 + 32);

#pragma unroll
    for (int ks = 0; ks < 2; ++ks)
#pragma unroll
      for (int nt = 0; nt < 8; ++nt) {
        short8 bv = *(const short8*)&lds[((ng * 8 + nt) * 16 + r15) * OUT_ST + ks * 32 + q * 8];
        acc[0][nt] = MFMA(ks ? a01 : a00, bv, acc[0][nt]);
        acc[1][nt] = MFMA(ks ? a11 : a10, bv, acc[1][nt]);
      }
    __syncthreads();
    if (e < 15) {
      stage_write();
      __syncthreads();
    }
  }

#pragma unroll
  for (int mt = 0; mt < 2; ++mt) {
    const int v0 = vg * 32 + mt * 16 + q * 4;
#pragma unroll
    for (int nt = 0; nt < 8; ++nt) {
      const int i = i0 + (ng * 8 + nt) * 16 + r15;
      *(f32x4*)&agg[(size_t)i * 128 + v0] = acc[mt][nt];
    }
  }
}

// ---------------------------------------------------------------------------
// Kernel 3: out[n,o] = tanh(sum_k upd[n,k] * W_upd[o,k] + b_upd[o]).
// 6-partial variant: in = in0+in1, out = o0+o1+o2+o3 as extra K-slices.
// ---------------------------------------------------------------------------
__global__ __launch_bounds__(256) void final6_kernel(
    const float* __restrict__ in0, const float* __restrict__ in1,
    const unsigned short* __restrict__ node_rep,
    const float* __restrict__ o0, const float* __restrict__ o1,
    const float* __restrict__ o2, const float* __restrict__ o3,
    const float* __restrict__ W_upd,              // [128][384]
    const float* __restrict__ b_upd,              // [128]
    float* __restrict__ out)                      // [16384][128]
{
  const int tid  = threadIdx.x;
  const int lane = tid & 63;
  const int w    = tid >> 6;
  const int q    = lane >> 4;
  const int r15  = lane & 15;
  const int n0   = blockIdx.x * 32;

  const float* ibufs[2] = { in0, in1 };
  const float* obufs[4] = { o0, o1, o2, o3 };

  f32x4 acc[2][2];
#pragma unroll
  for (int mt = 0; mt < 2; ++mt)
#pragma unroll
    for (int nt = 0; nt < 2; ++nt) acc[mt][nt] = (f32x4)0.0f;

#pragma unroll
  for (int ks = 0; ks < 12; ++ks) {
    const int s  = ks >> 2;              // 0:in 1:node 2:out
    const int kk = (ks & 3) * 32 + q * 8;
    short8 a[2];
#pragma unroll
    for (int mt = 0; mt < 2; ++mt) {
      const float* p = W_upd + (size_t)(w * 32 + mt * 16 + r15) * 384 + ks * 32 + q * 8;
      a[mt] = pack8(*(const float4*)p, *(const float4*)(p + 4));
    }
#pragma unroll
    for (int nt = 0; nt < 2; ++nt) {
      const int g = n0 + nt * 16 + r15;
      if (s == 1) {
        short8 bv = *(const short8*)&node_rep[(size_t)g * 128 + kk];
        acc[0][nt] = MFMA(a[0], bv, acc[0][nt]);
        acc[1][nt] = MFMA(a[1], bv, acc[1][nt]);
      } else if (s == 0) {
#pragma unroll
        for (int u = 0; u < 2; ++u) {
          const float* pp = ibufs[u] + (size_t)g * 128 + kk;
          short8 bv = pack8(*(const float4*)pp, *(const float4*)(pp + 4));
          acc[0][nt] = MFMA(a[0], bv, acc[0][nt]);
          acc[1][nt] = MFMA(a[1], bv, acc[1][nt]);
        }
      } else {
#pragma unroll
        for (int u = 0; u < 4; ++u) {
          const float* pp = obufs[u] + (size_t)g * 128 + kk;
          short8 bv = pack8(*(const float4*)pp, *(const float4*)(pp + 4));
          acc[0][nt] = MFMA(a[0], bv, acc[0][nt]);
          acc[1][nt] = MFMA(a[1], bv, acc[1][nt]);
        }
      }
    }
  }

#pragma unroll
  for (int mt = 0; mt < 2; ++mt) {
    const int o0c = w * 32 + mt * 16 + q * 4;
#pragma unroll
    for (int nt = 0; nt < 2; ++nt) {
      const int g = n0 + nt * 16 + r15;
      f32x4 ov;
#pragma unroll
      for (int c = 0; c < 4; ++c) ov[c] = tanhf(acc[mt][nt][c] + b_upd[o0c + c]);
      *(f32x4*)&out[(size_t)g * 128 + o0c] = ov;
    }
  }
}

// ---------------------------------------------------------------------------
// Fallback path (ws < 60MB): proven R3 split-K=2 fused agg + final_split.
// ---------------------------------------------------------------------------
#define AGG_BK 128
#define AGG_ST 136
#define AGG_BUF (64 * AGG_ST)

template <bool TC>
__device__ __forceinline__ void agg_body(
    const float* __restrict__ adjb,
    const unsigned short* __restrict__ rep,
    float* __restrict__ agg,
    unsigned short* lds,
    int n0, int e0, int ne)
{
  const int tid  = threadIdx.x;
  const int lane = tid & 63;
  const int w    = tid >> 6;
  const int q    = lane >> 4;
  const int r15  = lane & 15;

  const unsigned short* arow[2];
#pragma unroll
  for (int mt = 0; mt < 2; ++mt)
    arow[mt] = rep + (size_t)(w * 32 + mt * 16 + r15) * 4096 + q * 8;

  int sti, stko, j0 = 0;
  const float* ld0; const float* ld1 = nullptr;
  if (!TC) {
    sti  = tid >> 2;
    stko = (tid & 3) * 32;
    ld0  = adjb + (size_t)(n0 + sti) * 4096 + stko;
  } else {
    j0   = (tid >> 2) * 2;
    sti  = (tid & 3) * 16;
    ld0  = adjb + (size_t)j0 * 4096 + n0 + sti;
    ld1  = ld0 + 4096;
  }

  f32x4 acc[2][4];
#pragma unroll
  for (int mt = 0; mt < 2; ++mt)
#pragma unroll
    for (int nt = 0; nt < 4; ++nt) acc[mt][nt] = (f32x4)0.0f;

  float4 pf[8];
  short8 a_cur[8], a_nxt[8];

  auto stage_load = [&](int e) {
    if (!TC) {
      const float* p = ld0 + e * AGG_BK;
#pragma unroll
      for (int s = 0; s < 8; ++s) pf[s] = ((const float4*)p)[s];
    } else {
      const float* p0 = ld0 + (size_t)e * AGG_BK * 4096;
      const float* p1 = ld1 + (size_t)e * AGG_BK * 4096;
#pragma unroll
      for (int s = 0; s < 4; ++s) { pf[s] = ((const float4*)p0)[s]; pf[4 + s] = ((const float4*)p1)[s]; }
    }
  };
  auto stage_write = [&](unsigned short* dst) {
    if (!TC) {
#pragma unroll
      for (int s = 0; s < 4; ++s)
        *(short8*)&dst[sti * AGG_ST + stko + s * 8] = pack8(pf[2 * s], pf[2 * s + 1]);
    } else {
      const float* r0 = (const float*)&pf[0];
      const float* r1 = (const float*)&pf[4];
#pragma unroll
      for (int c = 0; c < 16; ++c) {
        unsigned v = (unsigned)f2bf(r0[c]) | ((unsigned)f2bf(r1[c]) << 16);
        *(unsigned*)&dst[(sti + c) * AGG_ST + j0] = v;
      }
    }
  };
  auto load_a = [&](int e, short8* d) {
#pragma unroll
    for (int sub = 0; sub < 4; ++sub)
#pragma unroll
      for (int mt = 0; mt < 2; ++mt)
        d[sub * 2 + mt] = *(const short8*)(arow[mt] + e * AGG_BK + sub * 32);
  };

  stage_load(e0);
  load_a(e0, a_cur);
  stage_write(lds);
  __syncthreads();

  for (int ei = 0; ei < ne; ++ei) {
    const int e = e0 + ei;
    unsigned short* cur = lds + (ei & 1) * AGG_BUF;
    unsigned short* nxt = lds + ((ei & 1) ^ 1) * AGG_BUF;

    if (ei < ne - 1) { stage_load(e + 1); load_a(e + 1, a_nxt); }

#pragma unroll
    for (int sub = 0; sub < 4; ++sub)
#pragma unroll
      for (int nt = 0; nt < 4; ++nt) {
        short8 bv = *(const short8*)&cur[(nt * 16 + r15) * AGG_ST + sub * 32 + q * 8];
        acc[0][nt] = MFMA(a_cur[sub * 2 + 0], bv, acc[0][nt]);
        acc[1][nt] = MFMA(a_cur[sub * 2 + 1], bv, acc[1][nt]);
      }

    if (ei < ne - 1) {
      stage_write(nxt);
#pragma unroll
      for (int i = 0; i < 8; ++i) a_cur[i] = a_nxt[i];
    }
    __syncthreads();
  }

#pragma unroll
  for (int mt = 0; mt < 2; ++mt) {
    const int v0 = w * 32 + mt * 16 + q * 4;
#pragma unroll
    for (int nt = 0; nt < 4; ++nt) {
      const int i = n0 + nt * 16 + r15;
      *(f32x4*)&agg[(size_t)i * 128 + v0] = acc[mt][nt];
    }
  }
}

__global__ __launch_bounds__(256, 4) void agg_split_kernel(
    const float* __restrict__ adj,
    const unsigned short* __restrict__ in_rep_t,
    const unsigned short* __restrict__ out_rep_t,
    float* __restrict__ in0, float* __restrict__ in1,
    float* __restrict__ out0, float* __restrict__ out1)
{
  __shared__ unsigned short lds[2 * AGG_BUF];
  const int id = blockIdx.x;
  const bool tc = id >= 512;
  const int t   = id & 511;
  const int kh  = t >> 8;
  const int tt  = t & 255;
  const int b   = tt >> 6;
  const int n0  = (tt & 63) * 64;
  const float* adjb = adj + ((size_t)b << 24);
  const unsigned short* rep = (tc ? out_rep_t : in_rep_t) + ((size_t)b << 19);
  float* agg = (tc ? (kh ? out1 : out0) : (kh ? in1 : in0)) + ((size_t)b << 19);
  if (tc) agg_body<true >(adjb, rep, agg, lds, n0, kh * 16, 16);
  else    agg_body<false>(adjb, rep, agg, lds, n0, kh * 16, 16);
}

__global__ __launch_bounds__(256) void final_split_kernel(
    const float* __restrict__ in0, const float* __restrict__ in1,
    const unsigned short* __restrict__ node_rep,
    const float* __restrict__ out0, const float* __restrict__ out1,
    const float* __restrict__ W_upd,
    const float* __restrict__ b_upd,
    float* __restrict__ out)
{
  const int tid  = threadIdx.x;
  const int lane = tid & 63;
  const int w    = tid >> 6;
  const int q    = lane >> 4;
  const int r15  = lane & 15;
  const int n0   = blockIdx.x * 32;

  f32x4 acc[2][2];
#pragma unroll
  for (int mt = 0; mt < 2; ++mt)
#pragma unroll
    for (int nt = 0; nt < 2; ++nt) acc[mt][nt] = (f32x4)0.0f;

#pragma unroll
  for (int ks = 0; ks < 12; ++ks) {
    const int s  = ks >> 2;
    const int kk = (ks & 3) * 32 + q * 8;
    short8 a[2];
#pragma unroll
    for (int mt = 0; mt < 2; ++mt) {
      const float* p = W_upd + (size_t)(w * 32 + mt * 16 + r15) * 384 + ks * 32 + q * 8;
      a[mt] = pack8(*(const float4*)p, *(const float4*)(p + 4));
    }
#pragma unroll
    for (int nt = 0; nt < 2; ++nt) {
      const int g = n0 + nt * 16 + r15;
      if (s == 1) {
        short8 bv = *(const short8*)&node_rep[(size_t)g * 128 + kk];
        acc[0][nt] = MFMA(a[0], bv, acc[0][nt]);
        acc[1][nt] = MFMA(a[1], bv, acc[1][nt]);
      } else {
        const float* p0 = ((s == 0) ? in0 : out0) + (size_t)g * 128 + kk;
        const float* p1 = ((s == 0) ? in1 : out1) + (size_t)g * 128 + kk;
        short8 bv0 = pack8(*(const float4*)p0, *(const float4*)(p0 + 4));
        acc[0][nt] = MFMA(a[0], bv0, acc[0][nt]);
        acc[1][nt] = MFMA(a[1], bv0, acc[1][nt]);
        short8 bv1 = pack8(*(const float4*)p1, *(const float4*)(p1 + 4));
        acc[0][nt] = MFMA(a[0], bv1, acc[0][nt]);
        acc[1][nt] = MFMA(a[1], bv1, acc[1][nt]);
      }
    }
  }

#pragma unroll
  for (int mt = 0; mt < 2; ++mt) {
    const int o0c = w * 32 + mt * 16 + q * 4;
#pragma unroll
    for (int nt = 0; nt < 2; ++nt) {
      const int g = n0 + nt * 16 + r15;
      f32x4 ov;
#pragma unroll
      for (int c = 0; c < 4; ++c) ov[c] = tanhf(acc[mt][nt][c] + b_upd[o0c + c]);
      *(f32x4*)&out[(size_t)g * 128 + o0c] = ov;
    }
  }
}

// ---------------------------------------------------------------------------
extern "C" void kernel_launch(void* const* d_in, const int* in_sizes, int n_in,
                              void* d_out, int out_size, void* d_ws, size_t ws_size,
                              hipStream_t stream) {
  (void)in_sizes; (void)n_in; (void)out_size;
  const float* nodes  = (const float*)d_in[0];
  const float* adj    = (const float*)d_in[1];
  const float* W_in   = (const float*)d_in[2];
  const float* b_in   = (const float*)d_in[3];
  const float* W_out  = (const float*)d_in[4];
  const float* b_out  = (const float*)d_in[5];
  const float* W_node = (const float*)d_in[6];
  const float* b_node = (const float*)d_in[7];
  const float* W_upd  = (const float*)d_in[8];
  const float* b_upd  = (const float*)d_in[9];
  float* out = (float*)d_out;

  unsigned short* ws = (unsigned short*)d_ws;
  const size_t SZ = (size_t)4 * 128 * 4096;   // shorts per bf16 array (4 MB)
  const size_t FS = (size_t)4 * 4096 * 128;   // floats per fp32 agg array (8 MB)
  unsigned short* in_rep_t  = ws;
  unsigned short* out_rep_t = ws + SZ;
  unsigned short* node_rep  = ws + 2 * SZ;
  float* fb = (float*)(ws + 3 * SZ);

  proj_kernel<<<dim3(256, 3), 256, 0, stream>>>(
      nodes, W_in, b_in, W_out, b_out, W_node, b_node,
      in_rep_t, out_rep_t, node_rep);

  const size_t need6 = 3 * SZ * sizeof(unsigned short) + 6 * FS * sizeof(float); // 60MB
  const size_t need4 = 3 * SZ * sizeof(unsigned short) + 4 * FS * sizeof(float); // 44MB
  if (ws_size >= need6) {
    float* in0 = fb;           float* in1 = fb + FS;
    float* o0  = fb + 2 * FS;  float* o1  = fb + 3 * FS;
    float* o2  = fb + 4 * FS;  float* o3  = fb + 5 * FS;
    agg_in_kernel <<<512, 256, 0, stream>>>(adj, in_rep_t, in0, in1);
    agg_out_kernel<<<256, 512, 0, stream>>>(adj, out_rep_t, o0, o1, o2, o3);
    final6_kernel <<<512, 256, 0, stream>>>(in0, in1, node_rep, o0, o1, o2, o3,
                                            W_upd, b_upd, out);
  } else if (ws_size >= need4) {
    float* in0  = fb;          float* in1  = fb + FS;
    float* out0 = fb + 2 * FS; float* out1 = fb + 3 * FS;
    agg_split_kernel<<<1024, 256, 0, stream>>>(adj, in_rep_t, out_rep_t,
                                               in0, in1, out0, out1);
    final_split_kernel<<<512, 256, 0, stream>>>(in0, in1, node_rep, out0, out1,
                                                W_upd, b_upd, out);
  }
}

// Round 3
// 535.761 us; speedup vs baseline: 1.0106x; 1.0106x over previous
//
#include <hip/hip_runtime.h>
#include <hip/hip_bf16.h>

// GraphSageLayer on MI355X. B=4, N=4096, D_IN=REP=D_OUT=128.
// proj (nodes->3 reps, bf16) -> agg (adj @ in_rep, adj^T @ out_rep) -> final (concat @ W_upd^T, tanh).
// All matmuls via v_mfma_f32_16x16x32_bf16; fp32 converted to bf16 in flight.
//
// R5 (channel-alias fix): R3 proved occupancy is not the limit (2x waves -> +0%);
// R4 proved granule width is not the limit, that fillBuffer hits 6.7 TB/s (memory
// system fine), and that splitting directions loses L3 adj sharing (FETCH 353MB
// < 536MB raw in the fused kernel). Remaining theory: adj rows are 16KB apart
// (power-of-2); all in-direction blocks sweep the k-window in the same order, so
// at any instant the whole GPU reads the same 512-B low-address window mod 16KB
// -> only a fraction of HBM channels active (2.2 of 6.7 TB/s). Fix: fused R3
// structure + per-block k-sweep stagger (s = blockIdx & 15, epochs visited in
// rotated order). kh half (8KB bit) x 16 offsets (512B) tile the full 16KB
// stride space. Deterministic (s fixed per block).

typedef __attribute__((ext_vector_type(8))) short short8;
typedef __attribute__((ext_vector_type(4))) float f32x4;
typedef __attribute__((ext_vector_type(4))) unsigned short u16x4;

#define MFMA(a, b, c) __builtin_amdgcn_mfma_f32_16x16x32_bf16(a, b, c, 0, 0, 0)

__device__ __forceinline__ unsigned short f2bf(float x) {
  union { float f; unsigned u; } v; v.f = x;
  unsigned r = v.u + 0x7FFFu + ((v.u >> 16) & 1u);   // RNE to bf16
  return (unsigned short)(r >> 16);
}

__device__ __forceinline__ short8 pack8(float4 a, float4 b) {
  short8 v;
  v[0] = (short)f2bf(a.x); v[1] = (short)f2bf(a.y); v[2] = (short)f2bf(a.z); v[3] = (short)f2bf(a.w);
  v[4] = (short)f2bf(b.x); v[5] = (short)f2bf(b.y); v[6] = (short)f2bf(b.z); v[7] = (short)f2bf(b.w);
  return v;
}

// ---------------------------------------------------------------------------
// Kernel 1: projections. rep = elu(nodes @ W^T + b). grid=(256 m-tiles, 3).
// ---------------------------------------------------------------------------
__global__ __launch_bounds__(256) void proj_kernel(
    const float* __restrict__ nodes,   // [16384][128]
    const float* __restrict__ W_in, const float* __restrict__ b_in,
    const float* __restrict__ W_out, const float* __restrict__ b_out,
    const float* __restrict__ W_node, const float* __restrict__ b_node,
    unsigned short* __restrict__ in_rep_t,   // [4][128][4096]
    unsigned short* __restrict__ out_rep_t,  // [4][128][4096]
    unsigned short* __restrict__ node_rep)   // [4][4096][128]
{
  const int wsel = blockIdx.y;
  const float* W    = (wsel == 0) ? W_in  : (wsel == 1) ? W_out  : W_node;
  const float* bias = (wsel == 0) ? b_in  : (wsel == 1) ? b_out  : b_node;

  const int tid  = threadIdx.x;
  const int lane = tid & 63;
  const int w    = tid >> 6;
  const int q    = lane >> 4;
  const int r15  = lane & 15;
  const int m0   = blockIdx.x * 64 + w * 16;

  f32x4 acc[8];
#pragma unroll
  for (int nt = 0; nt < 8; ++nt) acc[nt] = (f32x4)0.0f;

  short8 a[4];
#pragma unroll
  for (int ks = 0; ks < 4; ++ks) {
    const float* p = nodes + (size_t)(m0 + r15) * 128 + ks * 32 + q * 8;
    a[ks] = pack8(*(const float4*)p, *(const float4*)(p + 4));
  }

#pragma unroll
  for (int ks = 0; ks < 4; ++ks)
#pragma unroll
    for (int nt = 0; nt < 8; ++nt) {
      const float* p = W + (size_t)(nt * 16 + r15) * 128 + ks * 32 + q * 8;
      short8 bv = pack8(*(const float4*)p, *(const float4*)(p + 4));
      acc[nt] = MFMA(a[ks], bv, acc[nt]);
    }

#pragma unroll
  for (int nt = 0; nt < 8; ++nt) {
    const int rcol = nt * 16 + r15;
    const float bv = bias[rcol];
    const int g0 = m0 + q * 4;
    float x[4];
#pragma unroll
    for (int c = 0; c < 4; ++c) {
      float t = acc[nt][c] + bv;
      x[c] = (t > 0.f) ? t : (expf(t) - 1.f);   // ELU
    }
    if (wsel < 2) {
      unsigned short* rep = (wsel == 0) ? in_rep_t : out_rep_t;
      const int b = g0 >> 12, j = g0 & 4095;
      u16x4 o;
#pragma unroll
      for (int c = 0; c < 4; ++c) o[c] = f2bf(x[c]);
      *(u16x4*)&rep[((size_t)b << 19) + (size_t)rcol * 4096 + j] = o;
    } else {
#pragma unroll
      for (int c = 0; c < 4; ++c)
        node_rep[(size_t)(g0 + c) * 128 + rcol] = f2bf(x[c]);
    }
  }
}

// ---------------------------------------------------------------------------
// Kernel 2: aggregations (fused, both directions in one launch for L3 adj
// sharing).
//   !TC: in_agg[i,v]  = sum_j adj[b][i][j] * in_rep[j][v]
//    TC: out_agg[i,v] = sum_j adj[b][j][i] * out_rep[j][v]
// BK=128 epochs, double-buffered LDS [i=64][k=128] bf16 stride 136
// (conflict-free b128 reads+writes). Epoch-ahead prefetch of adj tile +
// A-frags. K-sweep STAGGER: epochs visited in order e0 + ((ei+s) & (ne-1)) so
// concurrent blocks hit distinct 512-B low-address windows of the 16KB row
// stride (channel de-aliasing). fp32 partial stores (SPLIT) or bf16 (legacy).
// ---------------------------------------------------------------------------
#define AGG_BK 128
#define AGG_ST 136   // shorts per LDS row: 128 + 8 pad
#define AGG_BUF (64 * AGG_ST)

template <bool TC, bool SPLIT>
__device__ __forceinline__ void agg_body(
    const float* __restrict__ adjb,         // adj + b*2^24
    const unsigned short* __restrict__ rep, // rep_t + b*2^19
    void* __restrict__ agg,                 // fp32 partial (SPLIT) or bf16
    unsigned short* lds,                    // [2][AGG_BUF]
    int n0, int e0, int ne, int s)          // epochs e0..e0+ne, stagger s
{
  const int tid  = threadIdx.x;
  const int lane = tid & 63;
  const int w    = tid >> 6;
  const int q    = lane >> 4;
  const int r15  = lane & 15;

  const unsigned short* arow[2];
#pragma unroll
  for (int mt = 0; mt < 2; ++mt)
    arow[mt] = rep + (size_t)(w * 32 + mt * 16 + r15) * 4096 + q * 8;

  // staging geometry
  int sti, stko, j0 = 0;
  const float* ld0; const float* ld1 = nullptr;
  if (!TC) {              // tile adj[n0+i][e*128+k]: thread = row sti, 32 cols
    sti  = tid >> 2;                 // i in [0,64)
    stko = (tid & 3) * 32;           // k base {0,32,64,96}
    ld0  = adjb + (size_t)(n0 + sti) * 4096 + stko;
  } else {                // tile adj[e*128+j][n0+i]: thread = rows j0,j0+1 x 16 cols
    j0   = (tid >> 2) * 2;           // j in {0,2,...,126}
    sti  = (tid & 3) * 16;           // i base {0,16,32,48}
    ld0  = adjb + (size_t)j0 * 4096 + n0 + sti;
    ld1  = ld0 + 4096;
  }

  f32x4 acc[2][4];
#pragma unroll
  for (int mt = 0; mt < 2; ++mt)
#pragma unroll
    for (int nt = 0; nt < 4; ++nt) acc[mt][nt] = (f32x4)0.0f;

  float4 pf[8];
  short8 a_cur[8], a_nxt[8];

  auto stage_load = [&](int e) {
    if (!TC) {
      const float* p = ld0 + e * AGG_BK;
#pragma unroll
      for (int s2 = 0; s2 < 8; ++s2) pf[s2] = ((const float4*)p)[s2];
    } else {
      const float* p0 = ld0 + (size_t)e * AGG_BK * 4096;
      const float* p1 = ld1 + (size_t)e * AGG_BK * 4096;
#pragma unroll
      for (int s2 = 0; s2 < 4; ++s2) { pf[s2] = ((const float4*)p0)[s2]; pf[4 + s2] = ((const float4*)p1)[s2]; }
    }
  };
  auto stage_write = [&](unsigned short* dst) {
    if (!TC) {
#pragma unroll
      for (int s2 = 0; s2 < 4; ++s2)
        *(short8*)&dst[sti * AGG_ST + stko + s2 * 8] = pack8(pf[2 * s2], pf[2 * s2 + 1]);
    } else {
      const float* r0 = (const float*)&pf[0];   // row j0, 16 floats
      const float* r1 = (const float*)&pf[4];   // row j0+1
#pragma unroll
      for (int c = 0; c < 16; ++c) {
        unsigned v = (unsigned)f2bf(r0[c]) | ((unsigned)f2bf(r1[c]) << 16);
        *(unsigned*)&dst[(sti + c) * AGG_ST + j0] = v;  // element (i, j0/j0+1)
      }
    }
  };
  auto load_a = [&](int e, short8* d) {
#pragma unroll
    for (int sub = 0; sub < 4; ++sub)
#pragma unroll
      for (int mt = 0; mt < 2; ++mt)
        d[sub * 2 + mt] = *(const short8*)(arow[mt] + e * AGG_BK + sub * 32);
  };

  const int mask = ne - 1;              // ne is a power of two (16 or 32)
  const int efirst = e0 + ((s) & mask);
  stage_load(efirst);
  load_a(efirst, a_cur);
  stage_write(lds);
  __syncthreads();

  for (int ei = 0; ei < ne; ++ei) {
    unsigned short* cur = lds + (ei & 1) * AGG_BUF;
    unsigned short* nxt = lds + ((ei & 1) ^ 1) * AGG_BUF;

    if (ei < ne - 1) {
      const int enext = e0 + ((ei + 1 + s) & mask);
      stage_load(enext);
      load_a(enext, a_nxt);
    }

#pragma unroll
    for (int sub = 0; sub < 4; ++sub)
#pragma unroll
      for (int nt = 0; nt < 4; ++nt) {
        short8 bv = *(const short8*)&cur[(nt * 16 + r15) * AGG_ST + sub * 32 + q * 8];
        acc[0][nt] = MFMA(a_cur[sub * 2 + 0], bv, acc[0][nt]);
        acc[1][nt] = MFMA(a_cur[sub * 2 + 1], bv, acc[1][nt]);
      }

    if (ei < ne - 1) {
      stage_write(nxt);
#pragma unroll
      for (int i = 0; i < 8; ++i) a_cur[i] = a_nxt[i];
    }
    __syncthreads();
  }

  // epilogue: agg[b][i][v], 4 consecutive v per lane
#pragma unroll
  for (int mt = 0; mt < 2; ++mt) {
    const int v0 = w * 32 + mt * 16 + q * 4;
#pragma unroll
    for (int nt = 0; nt < 4; ++nt) {
      const int i = n0 + nt * 16 + r15;
      if (SPLIT) {
        float* aggf = (float*)agg;
        *(f32x4*)&aggf[(size_t)i * 128 + v0] = acc[mt][nt];   // 16B fp32 partial
      } else {
        unsigned short* aggh = (unsigned short*)agg;
        u16x4 o;
#pragma unroll
        for (int c = 0; c < 4; ++c) o[c] = f2bf(acc[mt][nt][c]);
        *(u16x4*)&aggh[(size_t)i * 128 + v0] = o;             // 8B bf16
      }
    }
  }
}

// split-K=2, 1024 blocks (4 blocks/CU). s = id & 15: with kh providing the
// 8KB bit, the 16 offsets x 512B tile the full 16KB stride space.
__global__ __launch_bounds__(256, 4) void agg_split_kernel(
    const float* __restrict__ adj,
    const unsigned short* __restrict__ in_rep_t,
    const unsigned short* __restrict__ out_rep_t,
    float* __restrict__ in0, float* __restrict__ in1,
    float* __restrict__ out0, float* __restrict__ out1)
{
  __shared__ unsigned short lds[2 * AGG_BUF];
  const int id = blockIdx.x;            // [0,1024)
  const bool tc = id >= 512;
  const int t   = id & 511;
  const int kh  = t >> 8;               // K half: epochs [kh*16, kh*16+16)
  const int tt  = t & 255;
  const int b   = tt >> 6;
  const int n0  = (tt & 63) * 64;
  const int s   = id & 15;              // k-sweep stagger
  const float* adjb = adj + ((size_t)b << 24);
  const unsigned short* rep = (tc ? out_rep_t : in_rep_t) + ((size_t)b << 19);
  float* agg = (tc ? (kh ? out1 : out0) : (kh ? in1 : in0)) + ((size_t)b << 19);
  if (tc) agg_body<true,  true>(adjb, rep, agg, lds, n0, kh * 16, 16, s);
  else    agg_body<false, true>(adjb, rep, agg, lds, n0, kh * 16, 16, s);
}

// legacy split-1 path (used only if workspace is too small for fp32 partials)
__global__ __launch_bounds__(256, 2) void agg_kernel(
    const float* __restrict__ adj,
    const unsigned short* __restrict__ in_rep_t,
    const unsigned short* __restrict__ out_rep_t,
    unsigned short* __restrict__ in_agg,
    unsigned short* __restrict__ out_agg)
{
  __shared__ unsigned short lds[2 * AGG_BUF];
  const int id = blockIdx.x;
  const bool tc = (id >= 256);
  const int t  = id & 255;
  const int b  = t >> 6;
  const int n0 = (t & 63) * 64;
  const int s  = id & 31;
  const float* adjb = adj + ((size_t)b << 24);
  if (tc)
    agg_body<true,  false>(adjb, out_rep_t + ((size_t)b << 19), out_agg + ((size_t)b << 19), lds, n0, 0, 32, s);
  else
    agg_body<false, false>(adjb, in_rep_t + ((size_t)b << 19), in_agg + ((size_t)b << 19), lds, n0, 0, 32, s);
}

// ---------------------------------------------------------------------------
// Kernel 3: out[n,o] = tanh(sum_k upd[n,k] * W_upd[o,k] + b_upd[o]).
// Split variant: in_agg = in0+in1, out_agg = out0+out1 consumed as extra
// K-slices against the SAME W_upd columns (matmul linear in upd).
// ---------------------------------------------------------------------------
__global__ __launch_bounds__(256) void final_split_kernel(
    const float* __restrict__ in0, const float* __restrict__ in1,
    const unsigned short* __restrict__ node_rep,
    const float* __restrict__ out0, const float* __restrict__ out1,
    const float* __restrict__ W_upd,              // [128][384]
    const float* __restrict__ b_upd,              // [128]
    float* __restrict__ out)                      // [16384][128]
{
  const int tid  = threadIdx.x;
  const int lane = tid & 63;
  const int w    = tid >> 6;
  const int q    = lane >> 4;
  const int r15  = lane & 15;
  const int n0   = blockIdx.x * 32;

  f32x4 acc[2][2];
#pragma unroll
  for (int mt = 0; mt < 2; ++mt)
#pragma unroll
    for (int nt = 0; nt < 2; ++nt) acc[mt][nt] = (f32x4)0.0f;

#pragma unroll
  for (int ks = 0; ks < 12; ++ks) {
    const int s  = ks >> 2;              // 0:in 1:node 2:out
    const int kk = (ks & 3) * 32 + q * 8;
    short8 a[2];
#pragma unroll
    for (int mt = 0; mt < 2; ++mt) {
      const float* p = W_upd + (size_t)(w * 32 + mt * 16 + r15) * 384 + ks * 32 + q * 8;
      a[mt] = pack8(*(const float4*)p, *(const float4*)(p + 4));
    }
#pragma unroll
    for (int nt = 0; nt < 2; ++nt) {
      const int g = n0 + nt * 16 + r15;
      if (s == 1) {
        short8 bv = *(const short8*)&node_rep[(size_t)g * 128 + kk];
        acc[0][nt] = MFMA(a[0], bv, acc[0][nt]);
        acc[1][nt] = MFMA(a[1], bv, acc[1][nt]);
      } else {
        const float* p0 = ((s == 0) ? in0 : out0) + (size_t)g * 128 + kk;
        const float* p1 = ((s == 0) ? in1 : out1) + (size_t)g * 128 + kk;
        short8 bv0 = pack8(*(const float4*)p0, *(const float4*)(p0 + 4));
        acc[0][nt] = MFMA(a[0], bv0, acc[0][nt]);
        acc[1][nt] = MFMA(a[1], bv0, acc[1][nt]);
        short8 bv1 = pack8(*(const float4*)p1, *(const float4*)(p1 + 4));
        acc[0][nt] = MFMA(a[0], bv1, acc[0][nt]);
        acc[1][nt] = MFMA(a[1], bv1, acc[1][nt]);
      }
    }
  }

#pragma unroll
  for (int mt = 0; mt < 2; ++mt) {
    const int o0c = w * 32 + mt * 16 + q * 4;
#pragma unroll
    for (int nt = 0; nt < 2; ++nt) {
      const int g = n0 + nt * 16 + r15;
      f32x4 ov;
#pragma unroll
      for (int c = 0; c < 4; ++c) ov[c] = tanhf(acc[mt][nt][c] + b_upd[o0c + c]);
      *(f32x4*)&out[(size_t)g * 128 + o0c] = ov;
    }
  }
}

// legacy final (bf16 aggs)
__global__ __launch_bounds__(256) void final_kernel(
    const unsigned short* __restrict__ in_agg,
    const unsigned short* __restrict__ node_rep,
    const unsigned short* __restrict__ out_agg,
    const float* __restrict__ W_upd,
    const float* __restrict__ b_upd,
    float* __restrict__ out)
{
  const int tid  = threadIdx.x;
  const int lane = tid & 63;
  const int w    = tid >> 6;
  const int q    = lane >> 4;
  const int r15  = lane & 15;
  const int n0   = blockIdx.x * 32;

  const unsigned short* srcs[3] = { in_agg, node_rep, out_agg };

  f32x4 acc[2][2];
#pragma unroll
  for (int mt = 0; mt < 2; ++mt)
#pragma unroll
    for (int nt = 0; nt < 2; ++nt) acc[mt][nt] = (f32x4)0.0f;

#pragma unroll
  for (int ks = 0; ks < 12; ++ks) {
    const unsigned short* src = srcs[ks >> 2];
    const int col0 = (ks & 3) * 32 + q * 8;
    short8 a[2];
#pragma unroll
    for (int mt = 0; mt < 2; ++mt) {
      const float* p = W_upd + (size_t)(w * 32 + mt * 16 + r15) * 384 + ks * 32 + q * 8;
      a[mt] = pack8(*(const float4*)p, *(const float4*)(p + 4));
    }
#pragma unroll
    for (int nt = 0; nt < 2; ++nt) {
      const int g = n0 + nt * 16 + r15;
      short8 bv = *(const short8*)&src[(size_t)g * 128 + col0];
      acc[0][nt] = MFMA(a[0], bv, acc[0][nt]);
      acc[1][nt] = MFMA(a[1], bv, acc[1][nt]);
    }
  }

#pragma unroll
  for (int mt = 0; mt < 2; ++mt) {
    const int o0c = w * 32 + mt * 16 + q * 4;
#pragma unroll
    for (int nt = 0; nt < 2; ++nt) {
      const int g = n0 + nt * 16 + r15;
      f32x4 ov;
#pragma unroll
      for (int c = 0; c < 4; ++c) ov[c] = tanhf(acc[mt][nt][c] + b_upd[o0c + c]);
      *(f32x4*)&out[(size_t)g * 128 + o0c] = ov;
    }
  }
}

// ---------------------------------------------------------------------------
extern "C" void kernel_launch(void* const* d_in, const int* in_sizes, int n_in,
                              void* d_out, int out_size, void* d_ws, size_t ws_size,
                              hipStream_t stream) {
  (void)in_sizes; (void)n_in; (void)out_size;
  const float* nodes  = (const float*)d_in[0];
  const float* adj    = (const float*)d_in[1];
  const float* W_in   = (const float*)d_in[2];
  const float* b_in   = (const float*)d_in[3];
  const float* W_out  = (const float*)d_in[4];
  const float* b_out  = (const float*)d_in[5];
  const float* W_node = (const float*)d_in[6];
  const float* b_node = (const float*)d_in[7];
  const float* W_upd  = (const float*)d_in[8];
  const float* b_upd  = (const float*)d_in[9];
  float* out = (float*)d_out;

  unsigned short* ws = (unsigned short*)d_ws;
  const size_t SZ = (size_t)4 * 128 * 4096;   // shorts per bf16 array (4 MB)
  const size_t FS = (size_t)4 * 4096 * 128;   // floats per fp32 agg array (8 MB)
  unsigned short* in_rep_t  = ws;
  unsigned short* out_rep_t = ws + SZ;
  unsigned short* node_rep  = ws + 2 * SZ;

  proj_kernel<<<dim3(256, 3), 256, 0, stream>>>(
      nodes, W_in, b_in, W_out, b_out, W_node, b_node,
      in_rep_t, out_rep_t, node_rep);

  const size_t need = 3 * SZ * sizeof(unsigned short) + 4 * FS * sizeof(float); // 44MB
  if (ws_size >= need) {
    float* fb = (float*)(ws + 3 * SZ);
    float* in0  = fb;
    float* in1  = fb + FS;
    float* out0 = fb + 2 * FS;
    float* out1 = fb + 3 * FS;
    agg_split_kernel<<<1024, 256, 0, stream>>>(adj, in_rep_t, out_rep_t,
                                               in0, in1, out0, out1);
    final_split_kernel<<<512, 256, 0, stream>>>(in0, in1, node_rep, out0, out1,
                                                W_upd, b_upd, out);
  } else {
    unsigned short* in_agg  = ws + 3 * SZ;
    unsigned short* out_agg = ws + 4 * SZ;
    agg_kernel<<<512, 256, 0, stream>>>(adj, in_rep_t, out_rep_t, in_agg, out_agg);
    final_kernel<<<512, 256, 0, stream>>>(in_agg, node_rep, out_agg, W_upd, b_upd, out);
  }
}

// Round 4
// 506.401 us; speedup vs baseline: 1.0692x; 1.0580x over previous
//
#include <hip/hip_runtime.h>
#include <hip/hip_bf16.h>

// GraphSageLayer on MI355X. B=4, N=4096, D_IN=REP=D_OUT=128.
// proj (nodes->3 reps, bf16) -> agg (adj @ in_rep, adj^T @ out_rep) -> final (concat @ W_upd^T, tanh).
//
// R6: stagger reverted (R5: zero BW change, +50MB FETCH -> channel-alias theory dead).
// Remaining theory: in-flight-bytes cap. agg VGPR_Count=64 proves the compiler SANK
// the register prefetch (pipeline depth ~0); per-CU in-flight ~4KB -> ~2.2 TB/s at
// ~1200cy loaded latency == observed cap, for both 2 and 4 blocks/CU. Fix: stage the
// in-direction adj tiles via global_load_lds (no VGPR landing zone, depth via counted
// vmcnt(8), raw s_barrier -- never vmcnt(0) in the main loop). fp32 lands in LDS with
// XOR-unit swizzle applied on the per-lane GLOBAL source (linear LDS dest, m173
// pattern); bf16 conversion on read via v_cvt_pk_bf16_f32 (VALU was 7% busy).
// TC (out) direction keeps the proven R3 reg-staged path; blocks interleaved
// even/odd in<->out so both directions stay co-resident for L3 adj sharing.

typedef __attribute__((ext_vector_type(8))) short short8;
typedef __attribute__((ext_vector_type(4))) float f32x4;
typedef __attribute__((ext_vector_type(4))) unsigned short u16x4;

#define MFMA(a, b, c) __builtin_amdgcn_mfma_f32_16x16x32_bf16(a, b, c, 0, 0, 0)

__device__ __forceinline__ unsigned short f2bf(float x) {
  union { float f; unsigned u; } v; v.f = x;
  unsigned r = v.u + 0x7FFFu + ((v.u >> 16) & 1u);   // RNE to bf16
  return (unsigned short)(r >> 16);
}

__device__ __forceinline__ short8 pack8(float4 a, float4 b) {
  short8 v;
  v[0] = (short)f2bf(a.x); v[1] = (short)f2bf(a.y); v[2] = (short)f2bf(a.z); v[3] = (short)f2bf(a.w);
  v[4] = (short)f2bf(b.x); v[5] = (short)f2bf(b.y); v[6] = (short)f2bf(b.z); v[7] = (short)f2bf(b.w);
  return v;
}

__device__ __forceinline__ void gll16(const float* g, void* l) {
  __builtin_amdgcn_global_load_lds(
      (const __attribute__((address_space(1))) unsigned int*)g,
      (__attribute__((address_space(3))) unsigned int*)l, 16, 0, 0);
}

// ---------------------------------------------------------------------------
// Kernel 1: projections. rep = elu(nodes @ W^T + b). grid=(256 m-tiles, 3).
// ---------------------------------------------------------------------------
__global__ __launch_bounds__(256) void proj_kernel(
    const float* __restrict__ nodes,   // [16384][128]
    const float* __restrict__ W_in, const float* __restrict__ b_in,
    const float* __restrict__ W_out, const float* __restrict__ b_out,
    const float* __restrict__ W_node, const float* __restrict__ b_node,
    unsigned short* __restrict__ in_rep_t,   // [4][128][4096]
    unsigned short* __restrict__ out_rep_t,  // [4][128][4096]
    unsigned short* __restrict__ node_rep)   // [4][4096][128]
{
  const int wsel = blockIdx.y;
  const float* W    = (wsel == 0) ? W_in  : (wsel == 1) ? W_out  : W_node;
  const float* bias = (wsel == 0) ? b_in  : (wsel == 1) ? b_out  : b_node;

  const int tid  = threadIdx.x;
  const int lane = tid & 63;
  const int w    = tid >> 6;
  const int q    = lane >> 4;
  const int r15  = lane & 15;
  const int m0   = blockIdx.x * 64 + w * 16;

  f32x4 acc[8];
#pragma unroll
  for (int nt = 0; nt < 8; ++nt) acc[nt] = (f32x4)0.0f;

  short8 a[4];
#pragma unroll
  for (int ks = 0; ks < 4; ++ks) {
    const float* p = nodes + (size_t)(m0 + r15) * 128 + ks * 32 + q * 8;
    a[ks] = pack8(*(const float4*)p, *(const float4*)(p + 4));
  }

#pragma unroll
  for (int ks = 0; ks < 4; ++ks)
#pragma unroll
    for (int nt = 0; nt < 8; ++nt) {
      const float* p = W + (size_t)(nt * 16 + r15) * 128 + ks * 32 + q * 8;
      short8 bv = pack8(*(const float4*)p, *(const float4*)(p + 4));
      acc[nt] = MFMA(a[ks], bv, acc[nt]);
    }

#pragma unroll
  for (int nt = 0; nt < 8; ++nt) {
    const int rcol = nt * 16 + r15;
    const float bv = bias[rcol];
    const int g0 = m0 + q * 4;
    float x[4];
#pragma unroll
    for (int c = 0; c < 4; ++c) {
      float t = acc[nt][c] + bv;
      x[c] = (t > 0.f) ? t : (expf(t) - 1.f);   // ELU
    }
    if (wsel < 2) {
      unsigned short* rep = (wsel == 0) ? in_rep_t : out_rep_t;
      const int b = g0 >> 12, j = g0 & 4095;
      u16x4 o;
#pragma unroll
      for (int c = 0; c < 4; ++c) o[c] = f2bf(x[c]);
      *(u16x4*)&rep[((size_t)b << 19) + (size_t)rcol * 4096 + j] = o;
    } else {
#pragma unroll
      for (int c = 0; c < 4; ++c)
        node_rep[(size_t)(g0 + c) * 128 + rcol] = f2bf(x[c]);
    }
  }
}

// ---------------------------------------------------------------------------
// in-direction body (gll deep pipeline):
//   in_agg[i,v] = sum_j adj[b][i][j] * in_rep[j][v]
// LDS: float F[2][64][128] linear (64KB). Per epoch (BK=128, 16 epochs/half):
//   1. MFMA: read fp32 from F[cur] (unit-XOR swizzle), cvt_pk->bf16, 32 MFMA
//   2. load_a(e+1) (rep rows, L2-hot, vmcnt-counted)
//   3. s_barrier (all waves done reading F[cur])
//   4. issue 8 gll(e+2) -> F[cur]
//   5. s_waitcnt vmcnt(8)  (gll(e+1) + a(e+1) landed; gll(e+2) stays in flight)
//   6. s_barrier; swap
// Swizzle: stored[row][u] = true[row][u ^ (row&15)] (32B units), applied on the
// per-lane gll source; read applies the same XOR -> b128 reads ~4-way max.
// ---------------------------------------------------------------------------
__device__ __forceinline__ void agg_in_gll(
    const float* __restrict__ adjb,         // adj + b*2^24
    const unsigned short* __restrict__ rep, // in_rep_t + b*2^19
    float* __restrict__ agg,                // fp32 partial + b*2^19
    unsigned char* smem, int n0, int kh)
{
  const int tid  = threadIdx.x;
  const int lane = tid & 63;
  const int w    = tid >> 6;
  const int q    = lane >> 4;
  const int r15  = lane & 15;

  const unsigned short* arow0 = rep + (size_t)(w * 32 + r15) * 4096 + kh * 2048 + q * 8;
  const unsigned short* arow1 = arow0 + (size_t)16 * 4096;

  const float* adjk = adjb + kh * 2048;

  f32x4 acc[2][4];
#pragma unroll
  for (int mt = 0; mt < 2; ++mt)
#pragma unroll
    for (int nt = 0; nt < 4; ++nt) acc[mt][nt] = (f32x4)0.0f;

  short8 a_cur[8], a_nxt[8];

  // per-lane gll source geometry (row within tile, unit swizzle)
  const int l5   = lane >> 5;          // chunk half (row parity)
  const int upos = (lane & 31) >> 1;   // 32B unit within row
  const int half = lane & 1;           // 16B half within unit

  auto issue = [&](int e, int buf) {
    const float* gb = adjk + (size_t)e * 128;
#pragma unroll
    for (int s = 0; s < 8; ++s) {
      const int row  = w * 16 + 2 * s + l5;
      const int usrc = upos ^ (row & 15);
      const float* g = gb + (size_t)(n0 + row) * 4096 + usrc * 8 + half * 4;
      gll16(g, smem + buf * 32768 + (w * 8 + s) * 1024);
    }
  };
  auto load_a = [&](int e, short8* d) {
#pragma unroll
    for (int sub = 0; sub < 4; ++sub) {
      d[sub * 2 + 0] = *(const short8*)(arow0 + e * 128 + sub * 32);
      d[sub * 2 + 1] = *(const short8*)(arow1 + e * 128 + sub * 32);
    }
  };

  issue(0, 0);
  load_a(0, a_cur);
  issue(1, 1);
  asm volatile("s_waitcnt vmcnt(8)" ::: "memory");   // gll(0)+a(0) done; gll(1) in flight
  __builtin_amdgcn_sched_barrier(0);
  __builtin_amdgcn_s_barrier();

  int cur = 0;
  for (int e = 0; e < 16; ++e) {
    const float* Fc = (const float*)(smem + cur * 32768);

#pragma unroll
    for (int sub = 0; sub < 4; ++sub)
#pragma unroll
      for (int nt = 0; nt < 4; ++nt) {
        const int row = nt * 16 + r15;
        const int u   = (sub * 4 + q) ^ r15;
        const float* fp = Fc + row * 128 + u * 8;
        f32x4 lo = *(const f32x4*)fp;
        f32x4 hi = *(const f32x4*)(fp + 4);
        union { unsigned u32[4]; short8 s8; } bu;
        asm("v_cvt_pk_bf16_f32 %0, %1, %2" : "=v"(bu.u32[0]) : "v"(lo[0]), "v"(lo[1]));
        asm("v_cvt_pk_bf16_f32 %0, %1, %2" : "=v"(bu.u32[1]) : "v"(lo[2]), "v"(lo[3]));
        asm("v_cvt_pk_bf16_f32 %0, %1, %2" : "=v"(bu.u32[2]) : "v"(hi[0]), "v"(hi[1]));
        asm("v_cvt_pk_bf16_f32 %0, %1, %2" : "=v"(bu.u32[3]) : "v"(hi[2]), "v"(hi[3]));
        acc[0][nt] = MFMA(a_cur[sub * 2 + 0], bu.s8, acc[0][nt]);
        acc[1][nt] = MFMA(a_cur[sub * 2 + 1], bu.s8, acc[1][nt]);
      }

    if (e < 15) load_a(e + 1, a_nxt);

    __builtin_amdgcn_sched_barrier(0);
    __builtin_amdgcn_s_barrier();          // all waves done reading F[cur]
    __builtin_amdgcn_sched_barrier(0);

    if (e < 14) {
      issue(e + 2, cur);                   // refill the buffer just drained
      asm volatile("s_waitcnt vmcnt(8)" ::: "memory");   // gll(e+1)+a(e+1) done
    } else {
      asm volatile("s_waitcnt vmcnt(0)" ::: "memory");   // tail drain
    }
    __builtin_amdgcn_sched_barrier(0);
    __builtin_amdgcn_s_barrier();          // F[nxt] valid for everyone
    __builtin_amdgcn_sched_barrier(0);

    cur ^= 1;
    if (e < 15) {
#pragma unroll
      for (int i = 0; i < 8; ++i) a_cur[i] = a_nxt[i];
    }
  }

  // epilogue: fp32 partial [i][v]
#pragma unroll
  for (int mt = 0; mt < 2; ++mt) {
    const int v0 = w * 32 + mt * 16 + q * 4;
#pragma unroll
    for (int nt = 0; nt < 4; ++nt) {
      const int i = n0 + nt * 16 + r15;
      *(f32x4*)&agg[(size_t)i * 128 + v0] = acc[mt][nt];
    }
  }
}

// ---------------------------------------------------------------------------
// R3 reg-staged body (TC direction + fallback). BK=128 epochs, double-buffered
// bf16 LDS stride 136, epoch-ahead register prefetch.
// ---------------------------------------------------------------------------
#define AGG_BK 128
#define AGG_ST 136
#define AGG_BUF (64 * AGG_ST)

template <bool TC, bool SPLIT>
__device__ __forceinline__ void agg_body(
    const float* __restrict__ adjb,
    const unsigned short* __restrict__ rep,
    void* __restrict__ agg,
    unsigned short* lds,
    int n0, int e0, int ne)
{
  const int tid  = threadIdx.x;
  const int lane = tid & 63;
  const int w    = tid >> 6;
  const int q    = lane >> 4;
  const int r15  = lane & 15;

  const unsigned short* arow[2];
#pragma unroll
  for (int mt = 0; mt < 2; ++mt)
    arow[mt] = rep + (size_t)(w * 32 + mt * 16 + r15) * 4096 + q * 8;

  int sti, stko, j0 = 0;
  const float* ld0; const float* ld1 = nullptr;
  if (!TC) {
    sti  = tid >> 2;
    stko = (tid & 3) * 32;
    ld0  = adjb + (size_t)(n0 + sti) * 4096 + stko;
  } else {
    j0   = (tid >> 2) * 2;
    sti  = (tid & 3) * 16;
    ld0  = adjb + (size_t)j0 * 4096 + n0 + sti;
    ld1  = ld0 + 4096;
  }

  f32x4 acc[2][4];
#pragma unroll
  for (int mt = 0; mt < 2; ++mt)
#pragma unroll
    for (int nt = 0; nt < 4; ++nt) acc[mt][nt] = (f32x4)0.0f;

  float4 pf[8];
  short8 a_cur[8], a_nxt[8];

  auto stage_load = [&](int e) {
    if (!TC) {
      const float* p = ld0 + e * AGG_BK;
#pragma unroll
      for (int s = 0; s < 8; ++s) pf[s] = ((const float4*)p)[s];
    } else {
      const float* p0 = ld0 + (size_t)e * AGG_BK * 4096;
      const float* p1 = ld1 + (size_t)e * AGG_BK * 4096;
#pragma unroll
      for (int s = 0; s < 4; ++s) { pf[s] = ((const float4*)p0)[s]; pf[4 + s] = ((const float4*)p1)[s]; }
    }
  };
  auto stage_write = [&](unsigned short* dst) {
    if (!TC) {
#pragma unroll
      for (int s = 0; s < 4; ++s)
        *(short8*)&dst[sti * AGG_ST + stko + s * 8] = pack8(pf[2 * s], pf[2 * s + 1]);
    } else {
      const float* r0 = (const float*)&pf[0];
      const float* r1 = (const float*)&pf[4];
#pragma unroll
      for (int c = 0; c < 16; ++c) {
        unsigned v = (unsigned)f2bf(r0[c]) | ((unsigned)f2bf(r1[c]) << 16);
        *(unsigned*)&dst[(sti + c) * AGG_ST + j0] = v;
      }
    }
  };
  auto load_a = [&](int e, short8* d) {
#pragma unroll
    for (int sub = 0; sub < 4; ++sub)
#pragma unroll
      for (int mt = 0; mt < 2; ++mt)
        d[sub * 2 + mt] = *(const short8*)(arow[mt] + e * AGG_BK + sub * 32);
  };

  stage_load(e0);
  load_a(e0, a_cur);
  stage_write(lds);
  __syncthreads();

  for (int ei = 0; ei < ne; ++ei) {
    const int e = e0 + ei;
    unsigned short* cur = lds + (ei & 1) * AGG_BUF;
    unsigned short* nxt = lds + ((ei & 1) ^ 1) * AGG_BUF;

    if (ei < ne - 1) { stage_load(e + 1); load_a(e + 1, a_nxt); }

#pragma unroll
    for (int sub = 0; sub < 4; ++sub)
#pragma unroll
      for (int nt = 0; nt < 4; ++nt) {
        short8 bv = *(const short8*)&cur[(nt * 16 + r15) * AGG_ST + sub * 32 + q * 8];
        acc[0][nt] = MFMA(a_cur[sub * 2 + 0], bv, acc[0][nt]);
        acc[1][nt] = MFMA(a_cur[sub * 2 + 1], bv, acc[1][nt]);
      }

    if (ei < ne - 1) {
      stage_write(nxt);
#pragma unroll
      for (int i = 0; i < 8; ++i) a_cur[i] = a_nxt[i];
    }
    __syncthreads();
  }

#pragma unroll
  for (int mt = 0; mt < 2; ++mt) {
    const int v0 = w * 32 + mt * 16 + q * 4;
#pragma unroll
    for (int nt = 0; nt < 4; ++nt) {
      const int i = n0 + nt * 16 + r15;
      if (SPLIT) {
        float* aggf = (float*)agg;
        *(f32x4*)&aggf[(size_t)i * 128 + v0] = acc[mt][nt];
      } else {
        unsigned short* aggh = (unsigned short*)agg;
        u16x4 o;
#pragma unroll
        for (int c = 0; c < 4; ++c) o[c] = f2bf(acc[mt][nt][c]);
        *(u16x4*)&aggh[(size_t)i * 128 + v0] = o;
      }
    }
  }
}

// split-K=2 fused kernel, 1024 blocks. Even ids = in (gll path), odd = out
// (reg-staged). Dynamic LDS 64KB -> 2 blocks/CU; both directions co-resident
// on every CU for L3 adj sharing.
__global__ __launch_bounds__(256, 2) void agg_split_kernel(
    const float* __restrict__ adj,
    const unsigned short* __restrict__ in_rep_t,
    const unsigned short* __restrict__ out_rep_t,
    float* __restrict__ in0, float* __restrict__ in1,
    float* __restrict__ out0, float* __restrict__ out1)
{
  extern __shared__ unsigned char smem[];
  const int id = blockIdx.x;            // [0,1024)
  const bool tc = (id & 1) != 0;
  const int rest = id >> 1;             // [0,512)
  const int kh  = rest >> 8;            // K half
  const int tt  = rest & 255;
  const int b   = tt >> 6;
  const int n0  = (tt & 63) * 64;
  const float* adjb = adj + ((size_t)b << 24);
  if (tc) {
    agg_body<true, true>(adjb, out_rep_t + ((size_t)b << 19),
                         (kh ? out1 : out0) + ((size_t)b << 19),
                         (unsigned short*)smem, n0, kh * 16, 16);
  } else {
    agg_in_gll(adjb, in_rep_t + ((size_t)b << 19),
               (kh ? in1 : in0) + ((size_t)b << 19),
               smem, n0, kh);
  }
}

// legacy split-1 path (workspace too small for fp32 partials)
__global__ __launch_bounds__(256, 2) void agg_kernel(
    const float* __restrict__ adj,
    const unsigned short* __restrict__ in_rep_t,
    const unsigned short* __restrict__ out_rep_t,
    unsigned short* __restrict__ in_agg,
    unsigned short* __restrict__ out_agg)
{
  __shared__ unsigned short lds[2 * AGG_BUF];
  const int id = blockIdx.x;
  const bool tc = (id >= 256);
  const int t  = id & 255;
  const int b  = t >> 6;
  const int n0 = (t & 63) * 64;
  const float* adjb = adj + ((size_t)b << 24);
  if (tc)
    agg_body<true,  false>(adjb, out_rep_t + ((size_t)b << 19), out_agg + ((size_t)b << 19), lds, n0, 0, 32);
  else
    agg_body<false, false>(adjb, in_rep_t + ((size_t)b << 19), in_agg + ((size_t)b << 19), lds, n0, 0, 32);
}

// ---------------------------------------------------------------------------
// Kernel 3: out[n,o] = tanh(sum_k upd[n,k] * W_upd[o,k] + b_upd[o]).
// Split variant: in = in0+in1, out = out0+out1 as extra K-slices.
// ---------------------------------------------------------------------------
__global__ __launch_bounds__(256) void final_split_kernel(
    const float* __restrict__ in0, const float* __restrict__ in1,
    const unsigned short* __restrict__ node_rep,
    const float* __restrict__ out0, const float* __restrict__ out1,
    const float* __restrict__ W_upd,              // [128][384]
    const float* __restrict__ b_upd,              // [128]
    float* __restrict__ out)                      // [16384][128]
{
  const int tid  = threadIdx.x;
  const int lane = tid & 63;
  const int w    = tid >> 6;
  const int q    = lane >> 4;
  const int r15  = lane & 15;
  const int n0   = blockIdx.x * 32;

  f32x4 acc[2][2];
#pragma unroll
  for (int mt = 0; mt < 2; ++mt)
#pragma unroll
    for (int nt = 0; nt < 2; ++nt) acc[mt][nt] = (f32x4)0.0f;

#pragma unroll
  for (int ks = 0; ks < 12; ++ks) {
    const int s  = ks >> 2;              // 0:in 1:node 2:out
    const int kk = (ks & 3) * 32 + q * 8;
    short8 a[2];
#pragma unroll
    for (int mt = 0; mt < 2; ++mt) {
      const float* p = W_upd + (size_t)(w * 32 + mt * 16 + r15) * 384 + ks * 32 + q * 8;
      a[mt] = pack8(*(const float4*)p, *(const float4*)(p + 4));
    }
#pragma unroll
    for (int nt = 0; nt < 2; ++nt) {
      const int g = n0 + nt * 16 + r15;
      if (s == 1) {
        short8 bv = *(const short8*)&node_rep[(size_t)g * 128 + kk];
        acc[0][nt] = MFMA(a[0], bv, acc[0][nt]);
        acc[1][nt] = MFMA(a[1], bv, acc[1][nt]);
      } else {
        const float* p0 = ((s == 0) ? in0 : out0) + (size_t)g * 128 + kk;
        const float* p1 = ((s == 0) ? in1 : out1) + (size_t)g * 128 + kk;
        short8 bv0 = pack8(*(const float4*)p0, *(const float4*)(p0 + 4));
        acc[0][nt] = MFMA(a[0], bv0, acc[0][nt]);
        acc[1][nt] = MFMA(a[1], bv0, acc[1][nt]);
        short8 bv1 = pack8(*(const float4*)p1, *(const float4*)(p1 + 4));
        acc[0][nt] = MFMA(a[0], bv1, acc[0][nt]);
        acc[1][nt] = MFMA(a[1], bv1, acc[1][nt]);
      }
    }
  }

#pragma unroll
  for (int mt = 0; mt < 2; ++mt) {
    const int o0c = w * 32 + mt * 16 + q * 4;
#pragma unroll
    for (int nt = 0; nt < 2; ++nt) {
      const int g = n0 + nt * 16 + r15;
      f32x4 ov;
#pragma unroll
      for (int c = 0; c < 4; ++c) ov[c] = tanhf(acc[mt][nt][c] + b_upd[o0c + c]);
      *(f32x4*)&out[(size_t)g * 128 + o0c] = ov;
    }
  }
}

// legacy final (bf16 aggs)
__global__ __launch_bounds__(256) void final_kernel(
    const unsigned short* __restrict__ in_agg,
    const unsigned short* __restrict__ node_rep,
    const unsigned short* __restrict__ out_agg,
    const float* __restrict__ W_upd,
    const float* __restrict__ b_upd,
    float* __restrict__ out)
{
  const int tid  = threadIdx.x;
  const int lane = tid & 63;
  const int w    = tid >> 6;
  const int q    = lane >> 4;
  const int r15  = lane & 15;
  const int n0   = blockIdx.x * 32;

  const unsigned short* srcs[3] = { in_agg, node_rep, out_agg };

  f32x4 acc[2][2];
#pragma unroll
  for (int mt = 0; mt < 2; ++mt)
#pragma unroll
    for (int nt = 0; nt < 2; ++nt) acc[mt][nt] = (f32x4)0.0f;

#pragma unroll
  for (int ks = 0; ks < 12; ++ks) {
    const unsigned short* src = srcs[ks >> 2];
    const int col0 = (ks & 3) * 32 + q * 8;
    short8 a[2];
#pragma unroll
    for (int mt = 0; mt < 2; ++mt) {
      const float* p = W_upd + (size_t)(w * 32 + mt * 16 + r15) * 384 + ks * 32 + q * 8;
      a[mt] = pack8(*(const float4*)p, *(const float4*)(p + 4));
    }
#pragma unroll
    for (int nt = 0; nt < 2; ++nt) {
      const int g = n0 + nt * 16 + r15;
      short8 bv = *(const short8*)&src[(size_t)g * 128 + col0];
      acc[0][nt] = MFMA(a[0], bv, acc[0][nt]);
      acc[1][nt] = MFMA(a[1], bv, acc[1][nt]);
    }
  }

#pragma unroll
  for (int mt = 0; mt < 2; ++mt) {
    const int o0c = w * 32 + mt * 16 + q * 4;
#pragma unroll
    for (int nt = 0; nt < 2; ++nt) {
      const int g = n0 + nt * 16 + r15;
      f32x4 ov;
#pragma unroll
      for (int c = 0; c < 4; ++c) ov[c] = tanhf(acc[mt][nt][c] + b_upd[o0c + c]);
      *(f32x4*)&out[(size_t)g * 128 + o0c] = ov;
    }
  }
}

// ---------------------------------------------------------------------------
extern "C" void kernel_launch(void* const* d_in, const int* in_sizes, int n_in,
                              void* d_out, int out_size, void* d_ws, size_t ws_size,
                              hipStream_t stream) {
  (void)in_sizes; (void)n_in; (void)out_size;
  const float* nodes  = (const float*)d_in[0];
  const float* adj    = (const float*)d_in[1];
  const float* W_in   = (const float*)d_in[2];
  const float* b_in   = (const float*)d_in[3];
  const float* W_out  = (const float*)d_in[4];
  const float* b_out  = (const float*)d_in[5];
  const float* W_node = (const float*)d_in[6];
  const float* b_node = (const float*)d_in[7];
  const float* W_upd  = (const float*)d_in[8];
  const float* b_upd  = (const float*)d_in[9];
  float* out = (float*)d_out;

  unsigned short* ws = (unsigned short*)d_ws;
  const size_t SZ = (size_t)4 * 128 * 4096;   // shorts per bf16 array (4 MB)
  const size_t FS = (size_t)4 * 4096 * 128;   // floats per fp32 agg array (8 MB)
  unsigned short* in_rep_t  = ws;
  unsigned short* out_rep_t = ws + SZ;
  unsigned short* node_rep  = ws + 2 * SZ;

  proj_kernel<<<dim3(256, 3), 256, 0, stream>>>(
      nodes, W_in, b_in, W_out, b_out, W_node, b_node,
      in_rep_t, out_rep_t, node_rep);

  const size_t need = 3 * SZ * sizeof(unsigned short) + 4 * FS * sizeof(float); // 44MB
  if (ws_size >= need) {
    float* fb = (float*)(ws + 3 * SZ);
    float* in0  = fb;
    float* in1  = fb + FS;
    float* out0 = fb + 2 * FS;
    float* out1 = fb + 3 * FS;
    agg_split_kernel<<<1024, 256, 65536, stream>>>(adj, in_rep_t, out_rep_t,
                                                   in0, in1, out0, out1);
    final_split_kernel<<<512, 256, 0, stream>>>(in0, in1, node_rep, out0, out1,
                                                W_upd, b_upd, out);
  } else {
    unsigned short* in_agg  = ws + 3 * SZ;
    unsigned short* out_agg = ws + 4 * SZ;
    agg_kernel<<<512, 256, 0, stream>>>(adj, in_rep_t, out_rep_t, in_agg, out_agg);
    final_kernel<<<512, 256, 0, stream>>>(in_agg, node_rep, out_agg, W_upd, b_upd, out);
  }
}